// Round 3
// baseline (262.844 us; speedup 1.0000x reference)
//
#include <hip/hip_runtime.h>
#include <hip/hip_bf16.h>

// Problem constants (from reference setup_inputs): B=8, C=3, H=W=512
#define HW    262144        // 512*512 (2^18)
#define HW4   65536         // HW/4 float4 elements per channel
#define BC    24            // B*C channels
#define NB    256           // bins
#define NTOT  6291456       // B*C*H*W

#define GH    128           // hist blocks per channel
#define GL    64            // loss blocks per channel

// Workspace layout (bytes):
//   [0, 24576)       hist_s : int[24][256]
//   [24576, 49152)   hist_r : int[24][256]
//   [49152, 49156)   accum  : float
//   [49156, 49252)   tix    : uint[24]   (hist completion tickets)
//   [49252, 49256)   tix2   : uint       (loss completion ticket)
//   [49280, 73856)   lut    : float[24][256]
#define WS_HS_OFF   0
#define WS_HR_OFF   24576
#define WS_ACC_OFF  49152
#define WS_TIX_OFF  49156
#define WS_TIX2_OFF 49252
#define WS_LUT_OFF  49280
#define WS_ZERO_BYTES 49256

__device__ __forceinline__ int quantize(float x, float m) {
    // jnp.clip(jnp.round((x+1)*0.5*255 * m), 0, 255)
    float v = (x + 1.0f) * 0.5f * 255.0f * m;
    float r = rintf(v);
    r = fminf(fmaxf(r, 0.0f), 255.0f);
    return (int)r;
}

__device__ __forceinline__ int incl_scan256(int v, int t, int* buf) {
    buf[t] = v;
    __syncthreads();
#pragma unroll
    for (int off = 1; off < NB; off <<= 1) {
        int x = (t >= off) ? buf[t - off] : 0;
        __syncthreads();
        buf[t] += x;
        __syncthreads();
    }
    return buf[t];
}

// ------------- Stage 1: fused per-channel histograms + matching LUT ---------
// grid dim3(GH, 24), block 256. Per-wave private LDS histograms; masked-out
// pixels counted in registers. Last block per channel (ticket) computes LUT.
__global__ void histlut_kernel(const float4* __restrict__ ref4,
                               const float4* __restrict__ tar4,
                               const float4* __restrict__ ms4,
                               const float4* __restrict__ mt4,
                               int* __restrict__ hs, int* __restrict__ hr,
                               unsigned* __restrict__ tix,
                               float* __restrict__ lut) {
    __shared__ int wh[4 * 2 * NB];        // [wave][s/r][bin]
    const int t = threadIdx.x;
    const int wave = t >> 6;
    const int lane = t & 63;
#pragma unroll
    for (int j = 0; j < 8; ++j) wh[t + j * 256] = 0;
    __syncthreads();

    const int c = blockIdx.y;
    const int b = c / 3;
    const float4* refc = ref4 + (size_t)c * HW4;
    const float4* tarc = tar4 + (size_t)c * HW4;
    const float4* msb  = ms4 + (size_t)b * HW4;
    const float4* mtb  = mt4 + (size_t)b * HW4;

    int* whS = &wh[wave * 512];
    int* whR = &wh[wave * 512 + 256];
    int n0s = 0, n0r = 0;

    for (int i = blockIdx.x * blockDim.x + t; i < HW4; i += GH * 256) {
        const float4 r  = refc[i];
        const float4 m  = msb[i];
        const float4 tv = tarc[i];
        const float4 mm = mtb[i];

        const float rv[4]  = {r.x, r.y, r.z, r.w};
        const float mv[4]  = {m.x, m.y, m.z, m.w};
        const float tvv[4] = {tv.x, tv.y, tv.z, tv.w};
        const float mtv[4] = {mm.x, mm.y, mm.z, mm.w};
#pragma unroll
        for (int k = 0; k < 4; ++k) {
            if (mv[k] != 0.0f) atomicAdd(&whS[quantize(rv[k], mv[k])], 1);
            else n0s++;
            if (mtv[k] != 0.0f) atomicAdd(&whR[quantize(tvv[k], mtv[k])], 1);
            else n0r++;
        }
    }
    // fold register bin-0 counts: wave-reduce then one LDS add per wave
#pragma unroll
    for (int off = 32; off > 0; off >>= 1) {
        n0s += __shfl_down(n0s, off);
        n0r += __shfl_down(n0r, off);
    }
    if (lane == 0) {
        if (n0s) atomicAdd(&whS[0], n0s);
        if (n0r) atomicAdd(&whR[0], n0r);
    }
    __syncthreads();

    // merge 4 wave-hists, one global atomic per occupied bin
    {
        const int s = wh[t] + wh[512 + t] + wh[1024 + t] + wh[1536 + t];
        const int r = wh[256 + t] + wh[768 + t] + wh[1280 + t] + wh[1792 + t];
        if (s) atomicAdd(&hs[c * NB + t], s);
        if (r) atomicAdd(&hr[c * NB + t], r);
    }

    // ticket: last block of this channel computes the LUT
    __shared__ unsigned last;
    __syncthreads();
    if (t == 0) {
        __threadfence();
        last = atomicAdd(&tix[c], 1u);
    }
    __syncthreads();
    if (last != GH - 1) return;
    __threadfence();   // acquire: make other blocks' hist atomics visible

    // ---- LUT phase (256 threads, thread t owns bin t) ----
    // alias scratch onto wh (no longer needed)
    int*   buf = wh;
    float* xp  = (float*)&wh[256];
    float* fp  = (float*)&wh[512];
    __shared__ int firstS, firstR, nOccS, nOccR;

    const int cs = atomicAdd(&hs[c * NB + t], 0);  // coherent read
    const int cr = atomicAdd(&hr[c * NB + t], 0);

    if (t == 0) { firstS = NB; firstR = NB; nOccS = 0; nOccR = 0; }
    __syncthreads();
    if (cs > 0) { atomicMin(&firstS, t); atomicAdd(&nOccS, 1); }
    if (cr > 0) { atomicMin(&firstR, t); atomicAdd(&nOccR, 1); }
    __syncthreads();

    const int csz = (t == firstS) ? 0 : cs;
    const int crz = (t == firstR) ? 0 : cr;

    const int cumS = incl_scan256(csz, t, buf);
    const int totS = buf[NB - 1];
    __syncthreads();
    const int cumR = incl_scan256(crz, t, buf);
    const int totR = buf[NB - 1];
    __syncthreads();
    const int occ2 = (cr > 0 && t != firstR) ? 1 : 0;
    const int rank = incl_scan256(occ2, t, buf) - occ2;  // exclusive
    __syncthreads();

    const float x  = (float)cumS / fmaxf((float)totS, 1.0f);
    const float rq = (float)cumR / fmaxf((float)totR, 1.0f);

    xp[t] = 2.0f;
    fp[t] = 0.0f;
    __syncthreads();
    if (occ2) { xp[rank] = rq; fp[rank] = (float)t; }
    __syncthreads();

    // jnp.interp semantics: searchsorted-right, i clipped to [1,255]
    int lo = 0, hi = NB;
    while (lo < hi) {
        int mid = (lo + hi) >> 1;
        if (xp[mid] > x) hi = mid; else lo = mid + 1;
    }
    int i = lo;
    i = (i < 1) ? 1 : ((i > NB - 1) ? NB - 1 : i);
    float dxv = xp[i] - xp[i - 1];
    float f;
    if (dxv == 0.0f) f = fp[i];
    else f = fp[i - 1] + (x - xp[i - 1]) / dxv * (fp[i] - fp[i - 1]);
    if (x < xp[0]) f = fp[0];

    float l = truncf(f);
    if (t == firstS) l = 0.0f;
    if (!((nOccS > 1) && (nOccR > 1))) l = 0.0f;

    lut[c * NB + t] = l;
}

// ------------- Stage 2: apply LUT + masked L1 reduction (+finalize) ---------
// grid dim3(GL, 24), block 256, 4 float4 per thread. Last block writes out.
__global__ void loss_kernel(const float4* __restrict__ inp4,
                            const float4* __restrict__ ref4,
                            const float4* __restrict__ ms4,
                            const float* __restrict__ lut,
                            float* __restrict__ accum,
                            unsigned* __restrict__ tix2,
                            float* __restrict__ out) {
    __shared__ float llut[NB];
    const int t = threadIdx.x;
    const int c = blockIdx.y;
    const int b = c / 3;
    llut[t] = lut[c * NB + t];
    __syncthreads();

    const float4* inpc = inp4 + (size_t)c * HW4;
    const float4* refc = ref4 + (size_t)c * HW4;
    const float4* msb  = ms4 + (size_t)b * HW4;

    float s = 0.0f;
    for (int i = blockIdx.x * blockDim.x + t; i < HW4; i += GL * 256) {
        const float4 x = inpc[i];
        const float4 r = refc[i];
        const float4 m = msb[i];
        const float xv[4] = {x.x, x.y, x.z, x.w};
        const float rv[4] = {r.x, r.y, r.z, r.w};
        const float mv[4] = {m.x, m.y, m.z, m.w};
#pragma unroll
        for (int k = 0; k < 4; ++k) {
            if (mv[k] != 0.0f) {
                const int q = quantize(rv[k], mv[k]);
                const float im = (xv[k] + 1.0f) * 127.5f;
                s += fabsf(im - llut[q]);
            }
        }
    }

#pragma unroll
    for (int off = 32; off > 0; off >>= 1) s += __shfl_down(s, off);
    __shared__ float wsum[4];
    const int lane = t & 63;
    const int wave = t >> 6;
    if (lane == 0) wsum[wave] = s;
    __syncthreads();
    if (t == 0) {
        const float bs = wsum[0] + wsum[1] + wsum[2] + wsum[3];
        atomicAdd(accum, bs);
        __threadfence();
        const unsigned done = atomicAdd(tix2, 1u);
        if (done == GL * BC - 1) {
            __threadfence();
            const float tot = atomicAdd(accum, 0.0f);  // coherent read
            out[0] = tot / (float)NTOT;
        }
    }
}

extern "C" void kernel_launch(void* const* d_in, const int* in_sizes, int n_in,
                              void* d_out, int out_size, void* d_ws, size_t ws_size,
                              hipStream_t stream) {
    const float* inp  = (const float*)d_in[0];
    const float* tar  = (const float*)d_in[1];
    const float* ref  = (const float*)d_in[2];
    const float* msrc = (const float*)d_in[3];
    const float* mtar = (const float*)d_in[4];

    char* ws = (char*)d_ws;
    int*      hs    = (int*)(ws + WS_HS_OFF);
    int*      hr    = (int*)(ws + WS_HR_OFF);
    float*    accum = (float*)(ws + WS_ACC_OFF);
    unsigned* tix   = (unsigned*)(ws + WS_TIX_OFF);
    unsigned* tix2  = (unsigned*)(ws + WS_TIX2_OFF);
    float*    lut   = (float*)(ws + WS_LUT_OFF);

    hipMemsetAsync(d_ws, 0, WS_ZERO_BYTES, stream);

    histlut_kernel<<<dim3(GH, BC), 256, 0, stream>>>(
        (const float4*)ref, (const float4*)tar,
        (const float4*)msrc, (const float4*)mtar, hs, hr, tix, lut);

    loss_kernel<<<dim3(GL, BC), 256, 0, stream>>>(
        (const float4*)inp, (const float4*)ref, (const float4*)msrc,
        lut, accum, tix2, (float*)d_out);
}

// Round 4
// 150.807 us; speedup vs baseline: 1.7429x; 1.7429x over previous
//
#include <hip/hip_runtime.h>
#include <hip/hip_bf16.h>

// Problem constants (from reference setup_inputs): B=8, C=3, H=W=512
#define HW    262144        // 512*512 (2^18)
#define HW4   65536         // HW/4 float4 elements per channel
#define BC    24            // B*C channels
#define NB    256           // bins
#define NTOT  6291456       // B*C*H*W

#define GH    64            // hist blocks per channel (4 float4/thread)
#define GL    64            // loss blocks per channel (4 float4/thread)

// Workspace layout (bytes):
//   [0, 24576)       hist_s : int[24][256]
//   [24576, 49152)   hist_r : int[24][256]
//   [49152, 49156)   accum  : float
//   [49216, 73792)   lut    : float[24][256]
#define WS_HS_OFF   0
#define WS_HR_OFF   24576
#define WS_ACC_OFF  49152
#define WS_LUT_OFF  49216
#define WS_ZERO_BYTES 49156

__device__ __forceinline__ int quantize(float x, float m) {
    // jnp.clip(jnp.round((x+1)*0.5*255 * m), 0, 255)
    float v = (x + 1.0f) * 0.5f * 255.0f * m;
    float r = rintf(v);
    r = fminf(fmaxf(r, 0.0f), 255.0f);
    return (int)r;
}

__device__ __forceinline__ int incl_scan256(int v, int t, int* buf) {
    buf[t] = v;
    __syncthreads();
#pragma unroll
    for (int off = 1; off < NB; off <<= 1) {
        int x = (t >= off) ? buf[t - off] : 0;
        __syncthreads();
        buf[t] += x;
        __syncthreads();
    }
    return buf[t];
}

// ---------------- Stage 1: per-channel histograms ----------------
// grid dim3(GH, 24), block 256. float4 loads; per-wave private LDS hists;
// masked-out pixels (all -> bin 0) counted in registers, folded per wave.
// NO fences / tickets — kernel boundary provides cross-XCD visibility.
__global__ void hist_kernel(const float4* __restrict__ ref4,
                            const float4* __restrict__ tar4,
                            const float4* __restrict__ ms4,
                            const float4* __restrict__ mt4,
                            int* __restrict__ hs, int* __restrict__ hr) {
    __shared__ int wh[4 * 2 * NB];        // [wave][s/r][bin]
    const int t = threadIdx.x;
    const int wave = t >> 6;
    const int lane = t & 63;
#pragma unroll
    for (int j = 0; j < 8; ++j) wh[t + j * 256] = 0;
    __syncthreads();

    const int c = blockIdx.y;
    const int b = c / 3;
    const float4* refc = ref4 + (size_t)c * HW4;
    const float4* tarc = tar4 + (size_t)c * HW4;
    const float4* msb  = ms4 + (size_t)b * HW4;
    const float4* mtb  = mt4 + (size_t)b * HW4;

    int* whS = &wh[wave * 512];
    int* whR = &wh[wave * 512 + 256];
    int n0s = 0, n0r = 0;

    for (int i = blockIdx.x * blockDim.x + t; i < HW4; i += GH * 256) {
        const float4 r  = refc[i];
        const float4 m  = msb[i];
        const float4 tv = tarc[i];
        const float4 mm = mtb[i];

        const float rv[4]  = {r.x, r.y, r.z, r.w};
        const float mv[4]  = {m.x, m.y, m.z, m.w};
        const float tvv[4] = {tv.x, tv.y, tv.z, tv.w};
        const float mtv[4] = {mm.x, mm.y, mm.z, mm.w};
#pragma unroll
        for (int k = 0; k < 4; ++k) {
            if (mv[k] != 0.0f) atomicAdd(&whS[quantize(rv[k], mv[k])], 1);
            else n0s++;
            if (mtv[k] != 0.0f) atomicAdd(&whR[quantize(tvv[k], mtv[k])], 1);
            else n0r++;
        }
    }
    // fold register bin-0 counts: wave-reduce, one LDS add per wave
#pragma unroll
    for (int off = 32; off > 0; off >>= 1) {
        n0s += __shfl_down(n0s, off);
        n0r += __shfl_down(n0r, off);
    }
    if (lane == 0) {
        if (n0s) atomicAdd(&whS[0], n0s);
        if (n0r) atomicAdd(&whR[0], n0r);
    }
    __syncthreads();

    // merge 4 wave-hists, one global atomic per occupied bin
    const int s = wh[t] + wh[512 + t] + wh[1024 + t] + wh[1536 + t];
    const int r = wh[256 + t] + wh[768 + t] + wh[1280 + t] + wh[1792 + t];
    if (s) atomicAdd(&hs[c * NB + t], s);
    if (r) atomicAdd(&hr[c * NB + t], r);
}

// ---------------- Stage 2: per-channel matching LUT ----------------
__global__ void lut_kernel(const int* __restrict__ hs,
                           const int* __restrict__ hr,
                           float* __restrict__ lut) {
    const int c = blockIdx.x;
    const int t = threadIdx.x;

    __shared__ int buf[NB];
    __shared__ float xp[NB];
    __shared__ float fp[NB];
    __shared__ int firstS, firstR, nOccS, nOccR;

    const int cs = hs[c * NB + t];
    const int cr = hr[c * NB + t];

    if (t == 0) { firstS = NB; firstR = NB; nOccS = 0; nOccR = 0; }
    __syncthreads();
    if (cs > 0) { atomicMin(&firstS, t); atomicAdd(&nOccS, 1); }
    if (cr > 0) { atomicMin(&firstR, t); atomicAdd(&nOccR, 1); }
    __syncthreads();

    const int csz = (t == firstS) ? 0 : cs;
    const int crz = (t == firstR) ? 0 : cr;

    const int cumS = incl_scan256(csz, t, buf);
    const int totS = buf[NB - 1];
    __syncthreads();
    const int cumR = incl_scan256(crz, t, buf);
    const int totR = buf[NB - 1];
    __syncthreads();
    const int occ2 = (cr > 0 && t != firstR) ? 1 : 0;
    const int rank = incl_scan256(occ2, t, buf) - occ2;  // exclusive
    __syncthreads();

    const float x  = (float)cumS / fmaxf((float)totS, 1.0f);
    const float rq = (float)cumR / fmaxf((float)totR, 1.0f);

    xp[t] = 2.0f;
    fp[t] = 0.0f;
    __syncthreads();
    if (occ2) { xp[rank] = rq; fp[rank] = (float)t; }
    __syncthreads();

    // jnp.interp semantics: searchsorted-right, i clipped to [1,255]
    int lo = 0, hi = NB;
    while (lo < hi) {
        int mid = (lo + hi) >> 1;
        if (xp[mid] > x) hi = mid; else lo = mid + 1;
    }
    int i = lo;
    i = (i < 1) ? 1 : ((i > NB - 1) ? NB - 1 : i);
    float dxv = xp[i] - xp[i - 1];
    float f;
    if (dxv == 0.0f) f = fp[i];
    else f = fp[i - 1] + (x - xp[i - 1]) / dxv * (fp[i] - fp[i - 1]);
    if (x < xp[0]) f = fp[0];

    float l = truncf(f);
    if (t == firstS) l = 0.0f;
    if (!((nOccS > 1) && (nOccR > 1))) l = 0.0f;

    lut[c * NB + t] = l;
}

// ---------------- Stage 3: apply LUT + masked L1 reduction ----------------
// grid dim3(GL, 24), block 256, 4 float4 per thread. Plain atomic accum.
__global__ void loss_kernel(const float4* __restrict__ inp4,
                            const float4* __restrict__ ref4,
                            const float4* __restrict__ ms4,
                            const float* __restrict__ lut,
                            float* __restrict__ accum) {
    __shared__ float llut[NB];
    const int t = threadIdx.x;
    const int c = blockIdx.y;
    const int b = c / 3;
    llut[t] = lut[c * NB + t];
    __syncthreads();

    const float4* inpc = inp4 + (size_t)c * HW4;
    const float4* refc = ref4 + (size_t)c * HW4;
    const float4* msb  = ms4 + (size_t)b * HW4;

    float s = 0.0f;
    for (int i = blockIdx.x * blockDim.x + t; i < HW4; i += GL * 256) {
        const float4 x = inpc[i];
        const float4 r = refc[i];
        const float4 m = msb[i];
        const float xv[4] = {x.x, x.y, x.z, x.w};
        const float rv[4] = {r.x, r.y, r.z, r.w};
        const float mv[4] = {m.x, m.y, m.z, m.w};
#pragma unroll
        for (int k = 0; k < 4; ++k) {
            if (mv[k] != 0.0f) {
                const int q = quantize(rv[k], mv[k]);
                const float im = (xv[k] + 1.0f) * 127.5f;
                s += fabsf(im - llut[q]);
            }
        }
    }

#pragma unroll
    for (int off = 32; off > 0; off >>= 1) s += __shfl_down(s, off);
    __shared__ float wsum[4];
    const int lane = t & 63;
    const int wave = t >> 6;
    if (lane == 0) wsum[wave] = s;
    __syncthreads();
    if (t == 0) atomicAdd(accum, wsum[0] + wsum[1] + wsum[2] + wsum[3]);
}

__global__ void finalize_kernel(const float* __restrict__ accum,
                                float* __restrict__ out) {
    out[0] = accum[0] / (float)NTOT;
}

extern "C" void kernel_launch(void* const* d_in, const int* in_sizes, int n_in,
                              void* d_out, int out_size, void* d_ws, size_t ws_size,
                              hipStream_t stream) {
    const float* inp  = (const float*)d_in[0];
    const float* tar  = (const float*)d_in[1];
    const float* ref  = (const float*)d_in[2];
    const float* msrc = (const float*)d_in[3];
    const float* mtar = (const float*)d_in[4];

    char* ws = (char*)d_ws;
    int*   hs    = (int*)(ws + WS_HS_OFF);
    int*   hr    = (int*)(ws + WS_HR_OFF);
    float* accum = (float*)(ws + WS_ACC_OFF);
    float* lut   = (float*)(ws + WS_LUT_OFF);

    hipMemsetAsync(d_ws, 0, WS_ZERO_BYTES, stream);

    hist_kernel<<<dim3(GH, BC), 256, 0, stream>>>(
        (const float4*)ref, (const float4*)tar,
        (const float4*)msrc, (const float4*)mtar, hs, hr);

    lut_kernel<<<BC, 256, 0, stream>>>(hs, hr, lut);

    loss_kernel<<<dim3(GL, BC), 256, 0, stream>>>(
        (const float4*)inp, (const float4*)ref, (const float4*)msrc,
        lut, accum);

    finalize_kernel<<<1, 1, 0, stream>>>(accum, (float*)d_out);
}

// Round 6
// 137.307 us; speedup vs baseline: 1.9143x; 1.0983x over previous
//
#include <hip/hip_runtime.h>
#include <hip/hip_bf16.h>

// Problem constants (from reference setup_inputs): B=8, C=3, H=W=512
#define HW    262144        // 512*512 (2^18)
#define HW4   65536         // HW/4 float4 elements per channel
#define BC    24            // B*C channels
#define NB    256           // bins
#define NTOT  6291456       // B*C*H*W

#define GH    64            // hist blocks per channel (4 float4/thread)
#define GL    64            // loss blocks per channel (4 float4/thread)

// Workspace layout (bytes) — nothing needs pre-zeroing:
//   [0, 1572864)         hsPart : int[24][GH][256]   per-block partial hists
//   [1572864, 3145728)   hrPart : int[24][GH][256]
//   [3145728, 3151872)   lsum   : float[24*GL]       per-block loss partials
//   [3151872, 3176448)   lut    : float[24][256]
// Total 3.03 MB; harness d_ws observed at ~268 MB (round-4 fill counters).
#define WS_HSP_OFF  0
#define WS_HRP_OFF  1572864
#define WS_LSUM_OFF 3145728
#define WS_LUT_OFF  3151872

__device__ __forceinline__ int quantize(float x, float m) {
    // jnp.clip(jnp.round((x+1)*0.5*255 * m), 0, 255)
    float v = (x + 1.0f) * 0.5f * 255.0f * m;
    float r = rintf(v);
    r = fminf(fmaxf(r, 0.0f), 255.0f);
    return (int)r;
}

__device__ __forceinline__ int incl_scan256(int v, int t, int* buf) {
    buf[t] = v;
    __syncthreads();
#pragma unroll
    for (int off = 1; off < NB; off <<= 1) {
        int x = (t >= off) ? buf[t - off] : 0;
        __syncthreads();
        buf[t] += x;
        __syncthreads();
    }
    return buf[t];
}

// ---------------- Stage 1: per-channel partial histograms ----------------
// grid dim3(GH, 24), block 256. All 16 float4 loads issued before use (MLP).
// Per-wave private LDS hists; masked-out pixels counted in registers.
// Block partial written with plain coalesced stores — no global atomics.
__global__ void __launch_bounds__(256)
hist_kernel(const float4* __restrict__ ref4,
            const float4* __restrict__ tar4,
            const float4* __restrict__ ms4,
            const float4* __restrict__ mt4,
            int* __restrict__ hsPart, int* __restrict__ hrPart) {
    __shared__ int wh[4 * 2 * NB];        // [wave][s/r][bin]
    const int t = threadIdx.x;
    const int wave = t >> 6;
    const int lane = t & 63;
#pragma unroll
    for (int j = 0; j < 8; ++j) wh[t + j * 256] = 0;
    __syncthreads();

    const int c = blockIdx.y;
    const int b = c / 3;
    const float4* refc = ref4 + (size_t)c * HW4;
    const float4* tarc = tar4 + (size_t)c * HW4;
    const float4* msb  = ms4 + (size_t)b * HW4;
    const float4* mtb  = mt4 + (size_t)b * HW4;

    const int base = blockIdx.x * 256 + t;   // stride GH*256 = 16384

    // ---- load phase: 16 independent float4 loads in flight ----
    float4 R[4], T[4], M[4], MT[4];
#pragma unroll
    for (int j = 0; j < 4; ++j) R[j]  = refc[base + j * 16384];
#pragma unroll
    for (int j = 0; j < 4; ++j) M[j]  = msb[base + j * 16384];
#pragma unroll
    for (int j = 0; j < 4; ++j) T[j]  = tarc[base + j * 16384];
#pragma unroll
    for (int j = 0; j < 4; ++j) MT[j] = mtb[base + j * 16384];

    // ---- process phase ----
    int* whS = &wh[wave * 512];
    int* whR = &wh[wave * 512 + 256];
    int n0s = 0, n0r = 0;
#pragma unroll
    for (int j = 0; j < 4; ++j) {
        const float rv[4]  = {R[j].x, R[j].y, R[j].z, R[j].w};
        const float mv[4]  = {M[j].x, M[j].y, M[j].z, M[j].w};
        const float tvv[4] = {T[j].x, T[j].y, T[j].z, T[j].w};
        const float mtv[4] = {MT[j].x, MT[j].y, MT[j].z, MT[j].w};
#pragma unroll
        for (int k = 0; k < 4; ++k) {
            if (mv[k] != 0.0f) atomicAdd(&whS[quantize(rv[k], mv[k])], 1);
            else n0s++;
            if (mtv[k] != 0.0f) atomicAdd(&whR[quantize(tvv[k], mtv[k])], 1);
            else n0r++;
        }
    }
    // fold register bin-0 counts: wave-reduce, one LDS add per wave
#pragma unroll
    for (int off = 32; off > 0; off >>= 1) {
        n0s += __shfl_down(n0s, off);
        n0r += __shfl_down(n0r, off);
    }
    if (lane == 0) {
        if (n0s) atomicAdd(&whS[0], n0s);
        if (n0r) atomicAdd(&whR[0], n0r);
    }
    __syncthreads();

    // merge 4 wave-hists -> per-block partial, plain coalesced store
    const int s = wh[t] + wh[512 + t] + wh[1024 + t] + wh[1536 + t];
    const int r = wh[256 + t] + wh[768 + t] + wh[1280 + t] + wh[1792 + t];
    hsPart[(c * GH + blockIdx.x) * NB + t] = s;
    hrPart[(c * GH + blockIdx.x) * NB + t] = r;
}

// ---------------- Stage 2: per-channel matching LUT ----------------
// 24 blocks; thread t owns bin t. Sums the GH partials, then scan/interp.
__global__ void __launch_bounds__(256)
lut_kernel(const int* __restrict__ hsPart,
           const int* __restrict__ hrPart,
           float* __restrict__ lut) {
    const int c = blockIdx.x;
    const int t = threadIdx.x;

    __shared__ int buf[NB];
    __shared__ float xp[NB];
    __shared__ float fp[NB];
    __shared__ int firstS, firstR, nOccS, nOccR;

    int cs = 0, cr = 0;
#pragma unroll 4
    for (int g = 0; g < GH; ++g) {
        cs += hsPart[(c * GH + g) * NB + t];
        cr += hrPart[(c * GH + g) * NB + t];
    }

    if (t == 0) { firstS = NB; firstR = NB; nOccS = 0; nOccR = 0; }
    __syncthreads();
    if (cs > 0) { atomicMin(&firstS, t); atomicAdd(&nOccS, 1); }
    if (cr > 0) { atomicMin(&firstR, t); atomicAdd(&nOccR, 1); }
    __syncthreads();

    const int csz = (t == firstS) ? 0 : cs;
    const int crz = (t == firstR) ? 0 : cr;

    const int cumS = incl_scan256(csz, t, buf);
    const int totS = buf[NB - 1];
    __syncthreads();
    const int cumR = incl_scan256(crz, t, buf);
    const int totR = buf[NB - 1];
    __syncthreads();
    const int occ2 = (cr > 0 && t != firstR) ? 1 : 0;
    const int rank = incl_scan256(occ2, t, buf) - occ2;  // exclusive
    __syncthreads();

    const float x  = (float)cumS / fmaxf((float)totS, 1.0f);
    const float rq = (float)cumR / fmaxf((float)totR, 1.0f);

    xp[t] = 2.0f;
    fp[t] = 0.0f;
    __syncthreads();
    if (occ2) { xp[rank] = rq; fp[rank] = (float)t; }
    __syncthreads();

    // jnp.interp semantics: searchsorted-right, i clipped to [1,255]
    int lo = 0, hi = NB;
    while (lo < hi) {
        int mid = (lo + hi) >> 1;
        if (xp[mid] > x) hi = mid; else lo = mid + 1;
    }
    int i = lo;
    i = (i < 1) ? 1 : ((i > NB - 1) ? NB - 1 : i);
    float dxv = xp[i] - xp[i - 1];
    float f;
    if (dxv == 0.0f) f = fp[i];
    else f = fp[i - 1] + (x - xp[i - 1]) / dxv * (fp[i] - fp[i - 1]);
    if (x < xp[0]) f = fp[0];

    float l = truncf(f);
    if (t == firstS) l = 0.0f;
    if (!((nOccS > 1) && (nOccR > 1))) l = 0.0f;

    lut[c * NB + t] = l;
}

// ---------------- Stage 3: apply LUT + masked L1, per-block partial ---------
// grid dim3(GL, 24), block 256. 12 independent float4 loads in flight.
// Branchless: contribution = m * |im - lut[q]| (m in {0,1}).
__global__ void __launch_bounds__(256)
loss_kernel(const float4* __restrict__ inp4,
            const float4* __restrict__ ref4,
            const float4* __restrict__ ms4,
            const float* __restrict__ lut,
            float* __restrict__ lsum) {
    __shared__ float llut[NB];
    const int t = threadIdx.x;
    const int c = blockIdx.y;
    const int b = c / 3;
    llut[t] = lut[c * NB + t];
    __syncthreads();

    const float4* inpc = inp4 + (size_t)c * HW4;
    const float4* refc = ref4 + (size_t)c * HW4;
    const float4* msb  = ms4 + (size_t)b * HW4;

    const int base = blockIdx.x * 256 + t;   // stride GL*256 = 16384

    float4 X[4], R[4], M[4];
#pragma unroll
    for (int j = 0; j < 4; ++j) X[j] = inpc[base + j * 16384];
#pragma unroll
    for (int j = 0; j < 4; ++j) R[j] = refc[base + j * 16384];
#pragma unroll
    for (int j = 0; j < 4; ++j) M[j] = msb[base + j * 16384];

    float s = 0.0f;
#pragma unroll
    for (int j = 0; j < 4; ++j) {
        const float xv[4] = {X[j].x, X[j].y, X[j].z, X[j].w};
        const float rv[4] = {R[j].x, R[j].y, R[j].z, R[j].w};
        const float mv[4] = {M[j].x, M[j].y, M[j].z, M[j].w};
#pragma unroll
        for (int k = 0; k < 4; ++k) {
            const int q = quantize(rv[k], mv[k]);        // q=0 when m=0
            const float im = (xv[k] + 1.0f) * 127.5f;
            s += mv[k] * fabsf(im - llut[q]);            // m in {0,1}
        }
    }

#pragma unroll
    for (int off = 32; off > 0; off >>= 1) s += __shfl_down(s, off);
    __shared__ float wsum[4];
    const int lane = t & 63;
    const int wave = t >> 6;
    if (lane == 0) wsum[wave] = s;
    __syncthreads();
    if (t == 0)
        lsum[c * GL + blockIdx.x] = wsum[0] + wsum[1] + wsum[2] + wsum[3];
}

// ---------------- Stage 4: final reduction ----------------
__global__ void __launch_bounds__(256)
finalize_kernel(const float* __restrict__ lsum, float* __restrict__ out) {
    const int t = threadIdx.x;
    float s = 0.0f;
#pragma unroll
    for (int i = t; i < BC * GL; i += 256) s += lsum[i];
#pragma unroll
    for (int off = 32; off > 0; off >>= 1) s += __shfl_down(s, off);
    __shared__ float wsum[4];
    const int lane = t & 63;
    const int wave = t >> 6;
    if (lane == 0) wsum[wave] = s;
    __syncthreads();
    if (t == 0)
        out[0] = (wsum[0] + wsum[1] + wsum[2] + wsum[3]) / (float)NTOT;
}

extern "C" void kernel_launch(void* const* d_in, const int* in_sizes, int n_in,
                              void* d_out, int out_size, void* d_ws, size_t ws_size,
                              hipStream_t stream) {
    const float* inp  = (const float*)d_in[0];
    const float* tar  = (const float*)d_in[1];
    const float* ref  = (const float*)d_in[2];
    const float* msrc = (const float*)d_in[3];
    const float* mtar = (const float*)d_in[4];

    char* ws = (char*)d_ws;
    int*   hsPart = (int*)(ws + WS_HSP_OFF);
    int*   hrPart = (int*)(ws + WS_HRP_OFF);
    float* lsum   = (float*)(ws + WS_LSUM_OFF);
    float* lut    = (float*)(ws + WS_LUT_OFF);

    hist_kernel<<<dim3(GH, BC), 256, 0, stream>>>(
        (const float4*)ref, (const float4*)tar,
        (const float4*)msrc, (const float4*)mtar, hsPart, hrPart);

    lut_kernel<<<BC, 256, 0, stream>>>(hsPart, hrPart, lut);

    loss_kernel<<<dim3(GL, BC), 256, 0, stream>>>(
        (const float4*)inp, (const float4*)ref, (const float4*)msrc,
        lut, lsum);

    finalize_kernel<<<1, 256, 0, stream>>>(lsum, (float*)d_out);
}